// Round 6
// baseline (106.890 us; speedup 1.0000x reference)
//
#include <hip/hip_runtime.h>
#include <hip/hip_bf16.h>

#define N_ROWS 8192   // inputs rows (n)
#define K_CENT 1024   // centers rows (m)
#define DIM    1024   // d (elements; == bytes in fp8)

typedef __attribute__((ext_vector_type(4))) float f32x4;
typedef __attribute__((ext_vector_type(8))) int   i32x8;
typedef __attribute__((ext_vector_type(4))) int   i32x4;

__device__ __forceinline__ void async_copy16(const void* g, void* l) {
    __builtin_amdgcn_global_load_lds(
        (const __attribute__((address_space(1))) unsigned int*)g,
        (__attribute__((address_space(3))) unsigned int*)l,
        16, 0, 0);
}

// ---- kernel 1: fp32 -> fp8 e4m3 (scale 2^0) + fp32-exact row norms ----
__global__ __launch_bounds__(256) void prep_kernel(
        const float* __restrict__ inputs, const float* __restrict__ centers,
        unsigned char* __restrict__ Bq, unsigned char* __restrict__ Aq,
        float* __restrict__ x_sq, float* __restrict__ c_sq) {
    const int row  = blockIdx.x * 4 + (threadIdx.x >> 6);
    const int lane = threadIdx.x & 63;
    const bool is_x = row < N_ROWS;
    const float* src = is_x ? (inputs + (size_t)row * DIM)
                            : (centers + (size_t)(row - N_ROWS) * DIM);
    unsigned char* dst = is_x ? (Bq + (size_t)row * DIM)
                              : (Aq + (size_t)(row - N_ROWS) * DIM);
    const float4* s4 = (const float4*)src + lane * 4;
    float s = 0.0f;
    unsigned w[4];
    #pragma unroll
    for (int j = 0; j < 4; ++j) {
        float4 v = s4[j];
        int pk = __builtin_amdgcn_cvt_pk_fp8_f32(v.x, v.y, 0, false);
        pk     = __builtin_amdgcn_cvt_pk_fp8_f32(v.z, v.w, pk, true);
        w[j] = (unsigned)pk;
        s += v.x*v.x + v.y*v.y + v.z*v.z + v.w*v.w;
    }
    *(uint4*)(dst + lane * 16) = make_uint4(w[0], w[1], w[2], w[3]);
    #pragma unroll
    for (int off = 32; off > 0; off >>= 1) s += __shfl_down(s, off, 64);
    if (lane == 0) {
        if (is_x) x_sq[row] = s;
        else      c_sq[row - N_ROWS] = s;
    }
}

// ---- kernel 2: MX-fp8 GEMM. B via LDS dbuf (global_load_lds, XOR swizzle);
//      A-fragments DIRECT from global (L2-resident, 1 MB) into registers,
//      software-pipelined one iter ahead. 128x128 tile, 4 waves, BK=128. ----
#define BM 128
#define BN 128
#define BK 128
#define NITER (DIM / BK)

__device__ __forceinline__ i32x8 pack8(i32x4 lo, i32x4 hi) {
    i32x8 f;
    f[0]=lo[0]; f[1]=lo[1]; f[2]=lo[2]; f[3]=lo[3];
    f[4]=hi[0]; f[5]=hi[1]; f[6]=hi[2]; f[7]=hi[3];
    return f;
}

__global__ __launch_bounds__(256, 2) void gemm_kernel(
        const unsigned char* __restrict__ Aq,   // K_CENT x DIM fp8
        const unsigned char* __restrict__ Bq,   // N_ROWS x DIM fp8
        const float* __restrict__ x_sq, const float* __restrict__ c_sq,
        float* __restrict__ out) {              // K_CENT x N_ROWS
    __shared__ unsigned char sB[2][BN * BK];    // 2 x 16 KB

    const int t    = threadIdx.x;
    const int lane = t & 63;
    const int wave = t >> 6;
    const int wm   = (wave >> 1) * 64;
    const int wn   = (wave & 1) * 64;
    const int m0   = blockIdx.y * BM;
    const int n0   = blockIdx.x * BN;
    const int quad = lane >> 4;
    const int l16  = lane & 15;

    // B staging: 1024 16-B units/iter, 4 per thread; XOR swizzle h^(r&7)
    const unsigned char* gB[4];
    int ldsB[4];
    #pragma unroll
    for (int i = 0; i < 4; ++i) {
        const int p = i * 256 + t;
        const int r = p >> 3;
        const int h = (p & 7) ^ (r & 7);
        gB[i] = Bq + (size_t)(n0 + r) * DIM + h * 16;
        ldsB[i] = p * 16;
    }

    // A-fragment per-lane global bases (row = m0+wm+mi*16+l16, kbyte = quad*32)
    const unsigned char* gAf[4];
    #pragma unroll
    for (int mi = 0; mi < 4; ++mi)
        gAf[mi] = Aq + (size_t)(m0 + wm + mi * 16 + l16) * DIM + quad * 32;

    // B fragment LDS phys offsets (16-B units XOR-swizzled within the row)
    const int off1 = (((quad << 1)    ) ^ (l16 & 7)) << 4;
    const int off2 = (((quad << 1) | 1) ^ (l16 & 7)) << 4;

    f32x4 acc[4][4] = {};                       // [mi][ni]

    // prologue: B(0) -> buf0 (DMA first), then A frags for iter 0
    #pragma unroll
    for (int i = 0; i < 4; ++i) async_copy16(gB[i], &sB[0][ldsB[i]]);
    i32x8 af_cur[4], af_nxt[4];
    #pragma unroll
    for (int mi = 0; mi < 4; ++mi)
        af_cur[mi] = pack8(*(const i32x4*)(gAf[mi]),
                           *(const i32x4*)(gAf[mi] + 16));

    #pragma unroll
    for (int it = 0; it < NITER; ++it) {
        __syncthreads();                        // publishes sB[it&1]

        if (it + 1 < NITER) {
            const int koff = (it + 1) * BK;     // compile-time in unrolled loop
            #pragma unroll
            for (int i = 0; i < 4; ++i)
                async_copy16(gB[i] + koff, &sB[(it + 1) & 1][ldsB[i]]);
            #pragma unroll
            for (int mi = 0; mi < 4; ++mi)
                af_nxt[mi] = pack8(*(const i32x4*)(gAf[mi] + koff),
                                   *(const i32x4*)(gAf[mi] + koff + 16));
        }

        const unsigned char* B = sB[it & 1];
        i32x8 bf[4];
        #pragma unroll
        for (int ni = 0; ni < 4; ++ni) {
            const int rowByte = (wn + ni * 16 + l16) << 7;
            bf[ni] = pack8(*(const i32x4*)(B + rowByte + off1),
                           *(const i32x4*)(B + rowByte + off2));
        }
        #pragma unroll
        for (int mi = 0; mi < 4; ++mi)
            #pragma unroll
            for (int ni = 0; ni < 4; ++ni)
                acc[mi][ni] = __builtin_amdgcn_mfma_scale_f32_16x16x128_f8f6f4(
                    af_cur[mi], bf[ni], acc[mi][ni],
                    0, 0, 0, 0x7F7F7F7F, 0, 0x7F7F7F7F);

        #pragma unroll
        for (int mi = 0; mi < 4; ++mi) af_cur[mi] = af_nxt[mi];
    }

    // epilogue: C/D layout col(n) = lane&15, row(m) = quad*4 + reg
    #pragma unroll
    for (int ni = 0; ni < 4; ++ni) {
        const int n = n0 + wn + ni * 16 + l16;
        const float xs = x_sq[n];
        #pragma unroll
        for (int mi = 0; mi < 4; ++mi) {
            const int mbase = m0 + wm + mi * 16 + quad * 4;
            #pragma unroll
            for (int r = 0; r < 4; ++r) {
                const int m = mbase + r;
                out[(size_t)m * N_ROWS + n] = 2.0f * acc[mi][ni][r] - c_sq[m] - xs;
            }
        }
    }
}

extern "C" void kernel_launch(void* const* d_in, const int* in_sizes, int n_in,
                              void* d_out, int out_size, void* d_ws, size_t ws_size,
                              hipStream_t stream) {
    const float* inputs  = (const float*)d_in[0];   // (8192, 1024) fp32
    const float* centers = (const float*)d_in[1];   // (1024, 1024) fp32
    float* out = (float*)d_out;                     // (1024, 8192) fp32

    unsigned char* Aq = (unsigned char*)d_ws;            // centers fp8: 1 MB
    unsigned char* Bq = Aq + (size_t)K_CENT * DIM;       // inputs fp8: 8 MB
    float* x_sq = (float*)(Bq + (size_t)N_ROWS * DIM);   // 8192
    float* c_sq = x_sq + N_ROWS;                         // 1024

    prep_kernel<<<(N_ROWS + K_CENT) / 4, 256, 0, stream>>>(
        inputs, centers, Bq, Aq, x_sq, c_sq);
    gemm_kernel<<<dim3(N_ROWS / BN, K_CENT / BM), 256, 0, stream>>>(
        Aq, Bq, x_sq, c_sq, out);
}

// Round 7
// 97.576 us; speedup vs baseline: 1.0955x; 1.0955x over previous
//
#include <hip/hip_runtime.h>
#include <hip/hip_bf16.h>

#define N_ROWS 8192   // inputs rows (n)
#define K_CENT 1024   // centers rows (m)
#define DIM    1024   // d (elements; == bytes in fp8)

typedef __attribute__((ext_vector_type(4))) float f32x4;
typedef __attribute__((ext_vector_type(8))) int   i32x8;
typedef __attribute__((ext_vector_type(4))) int   i32x4;

__device__ __forceinline__ void async_copy16(const void* g, void* l) {
    __builtin_amdgcn_global_load_lds(
        (const __attribute__((address_space(1))) unsigned int*)g,
        (__attribute__((address_space(3))) unsigned int*)l,
        16, 0, 0);
}

// ---- kernel 1: fp32 -> fp8 e4m3 (scale 2^0) + fp32-exact row norms ----
__global__ __launch_bounds__(256) void prep_kernel(
        const float* __restrict__ inputs, const float* __restrict__ centers,
        unsigned char* __restrict__ Bq, unsigned char* __restrict__ Aq,
        float* __restrict__ x_sq, float* __restrict__ c_sq) {
    const int row  = blockIdx.x * 4 + (threadIdx.x >> 6);
    const int lane = threadIdx.x & 63;
    const bool is_x = row < N_ROWS;
    const float* src = is_x ? (inputs + (size_t)row * DIM)
                            : (centers + (size_t)(row - N_ROWS) * DIM);
    unsigned char* dst = is_x ? (Bq + (size_t)row * DIM)
                              : (Aq + (size_t)(row - N_ROWS) * DIM);
    const float4* s4 = (const float4*)src + lane * 4;
    float s = 0.0f;
    unsigned w[4];
    #pragma unroll
    for (int j = 0; j < 4; ++j) {
        float4 v = s4[j];
        int pk = __builtin_amdgcn_cvt_pk_fp8_f32(v.x, v.y, 0, false);
        pk     = __builtin_amdgcn_cvt_pk_fp8_f32(v.z, v.w, pk, true);
        w[j] = (unsigned)pk;
        s += v.x*v.x + v.y*v.y + v.z*v.z + v.w*v.w;
    }
    *(uint4*)(dst + lane * 16) = make_uint4(w[0], w[1], w[2], w[3]);
    #pragma unroll
    for (int off = 32; off > 0; off >>= 1) s += __shfl_down(s, off, 64);
    if (lane == 0) {
        if (is_x) x_sq[row] = s;
        else      c_sq[row - N_ROWS] = s;
    }
}

// ---- kernel 2: MX-fp8 GEMM (R4 shell), operand-swapped epilogue ----
// out[m][n] = 2*sum_d A[m][d]*B[n][d] - c_sq[m] - x_sq[n]
// 128x128 tile, 4 waves (each 64x64 via 4x4 of 16x16x128 MFMAs), BK=128.
// Both A and B double-buffered via global_load_lds (XOR swizzle h^(r&7)).
// MFMA called as D = B_op x A_op with scale_a = 2^1 (bakes in the factor 2),
// so C/D: col(lane&15) = m, row(quad*4+reg) = n -> float4 stores along n.
#define BM 128
#define BN 128
#define BK 128
#define NITER (DIM / BK)

__device__ __forceinline__ i32x8 pack8(i32x4 lo, i32x4 hi) {
    i32x8 f;
    f[0]=lo[0]; f[1]=lo[1]; f[2]=lo[2]; f[3]=lo[3];
    f[4]=hi[0]; f[5]=hi[1]; f[6]=hi[2]; f[7]=hi[3];
    return f;
}

__global__ __launch_bounds__(256, 2) void gemm_kernel(
        const unsigned char* __restrict__ Aq,   // K_CENT x DIM fp8
        const unsigned char* __restrict__ Bq,   // N_ROWS x DIM fp8
        const float* __restrict__ x_sq, const float* __restrict__ c_sq,
        float* __restrict__ out) {              // K_CENT x N_ROWS
    __shared__ unsigned char sA[2][BM * BK];    // 2 x 16 KB
    __shared__ unsigned char sB[2][BN * BK];    // 2 x 16 KB

    const int t    = threadIdx.x;
    const int lane = t & 63;
    const int wave = t >> 6;
    const int wm   = (wave >> 1) * 64;
    const int wn   = (wave & 1) * 64;
    const int m0   = blockIdx.y * BM;
    const int n0   = blockIdx.x * BN;
    const int quad = lane >> 4;
    const int l16  = lane & 15;

    // staging: 1024 16-B units per matrix per iter; 4 per thread per matrix
    const unsigned char* gA[4];
    const unsigned char* gB[4];
    int ldsOff[4];
    #pragma unroll
    for (int i = 0; i < 4; ++i) {
        const int p = i * 256 + t;
        const int r = p >> 3;
        const int h = (p & 7) ^ (r & 7);
        gA[i] = Aq + (size_t)(m0 + r) * DIM + h * 16;
        gB[i] = Bq + (size_t)(n0 + r) * DIM + h * 16;
        ldsOff[i] = p * 16;
    }

    // fragment phys offsets: lane wants bytes [quad*32, quad*32+32) of its row
    const int off1 = (((quad << 1)    ) ^ (l16 & 7)) << 4;
    const int off2 = (((quad << 1) | 1) ^ (l16 & 7)) << 4;

    f32x4 acc[4][4] = {};                       // [mi][ni]

    #pragma unroll
    for (int i = 0; i < 4; ++i) {
        async_copy16(gA[i], &sA[0][ldsOff[i]]);
        async_copy16(gB[i], &sB[0][ldsOff[i]]);
    }

    #pragma unroll
    for (int it = 0; it < NITER; ++it) {
        __syncthreads();                        // publishes buf it&1

        if (it + 1 < NITER) {
            const int nb = (it + 1) & 1;
            const int koff = (it + 1) * BK;     // compile-time (full unroll)
            #pragma unroll
            for (int i = 0; i < 4; ++i) {
                async_copy16(gA[i] + koff, &sA[nb][ldsOff[i]]);
                async_copy16(gB[i] + koff, &sB[nb][ldsOff[i]]);
            }
        }

        const unsigned char* A = sA[it & 1];
        const unsigned char* B = sB[it & 1];
        i32x8 af[4], bf[4];
        #pragma unroll
        for (int mi = 0; mi < 4; ++mi) {
            const int rowByte = (wm + mi * 16 + l16) << 7;
            af[mi] = pack8(*(const i32x4*)(A + rowByte + off1),
                           *(const i32x4*)(A + rowByte + off2));
        }
        #pragma unroll
        for (int ni = 0; ni < 4; ++ni) {
            const int rowByte = (wn + ni * 16 + l16) << 7;
            bf[ni] = pack8(*(const i32x4*)(B + rowByte + off1),
                           *(const i32x4*)(B + rowByte + off2));
        }
        // D = B_op(A-arg) x A_op(B-arg); scale_a = 2^1 folds the "2*cross"
        #pragma unroll
        for (int mi = 0; mi < 4; ++mi)
            #pragma unroll
            for (int ni = 0; ni < 4; ++ni)
                acc[mi][ni] = __builtin_amdgcn_mfma_scale_f32_16x16x128_f8f6f4(
                    bf[ni], af[mi], acc[mi][ni],
                    0, 0,
                    0, 0x80808080,              // scale_a = 2^1
                    0, 0x7F7F7F7F);             // scale_b = 2^0
    }

    // epilogue: col(l16) = m, row(quad*4+reg) = n -> float4 store along n
    #pragma unroll
    for (int mi = 0; mi < 4; ++mi) {
        const int m = m0 + wm + mi * 16 + l16;
        const float cs = c_sq[m];
        float* orow = out + (size_t)m * N_ROWS;
        #pragma unroll
        for (int ni = 0; ni < 4; ++ni) {
            const int n = n0 + wn + ni * 16 + quad * 4;
            const float4 xs = *(const float4*)(x_sq + n);
            const f32x4 a = acc[mi][ni];        // a = 2*cross already
            float4 res;
            res.x = a[0] - cs - xs.x;
            res.y = a[1] - cs - xs.y;
            res.z = a[2] - cs - xs.z;
            res.w = a[3] - cs - xs.w;
            *(float4*)(orow + n) = res;
        }
    }
}

extern "C" void kernel_launch(void* const* d_in, const int* in_sizes, int n_in,
                              void* d_out, int out_size, void* d_ws, size_t ws_size,
                              hipStream_t stream) {
    const float* inputs  = (const float*)d_in[0];   // (8192, 1024) fp32
    const float* centers = (const float*)d_in[1];   // (1024, 1024) fp32
    float* out = (float*)d_out;                     // (1024, 8192) fp32

    unsigned char* Aq = (unsigned char*)d_ws;            // centers fp8: 1 MB
    unsigned char* Bq = Aq + (size_t)K_CENT * DIM;       // inputs fp8: 8 MB
    float* x_sq = (float*)(Bq + (size_t)N_ROWS * DIM);   // 8192
    float* c_sq = x_sq + N_ROWS;                         // 1024

    prep_kernel<<<(N_ROWS + K_CENT) / 4, 256, 0, stream>>>(
        inputs, centers, Bq, Aq, x_sq, c_sq);
    gemm_kernel<<<dim3(N_ROWS / BN, K_CENT / BM), 256, 0, stream>>>(
        Aq, Bq, x_sq, c_sq, out);
}

// Round 8
// 97.156 us; speedup vs baseline: 1.1002x; 1.0043x over previous
//
#include <hip/hip_runtime.h>
#include <hip/hip_bf16.h>

#define N_ROWS 8192   // inputs rows (n)
#define K_CENT 1024   // centers rows (m)
#define DIM    1024   // d (elements; == bytes in fp8)

typedef __attribute__((ext_vector_type(4))) float f32x4;
typedef __attribute__((ext_vector_type(8))) int   i32x8;
typedef __attribute__((ext_vector_type(4))) int   i32x4;

__device__ __forceinline__ void async_copy16(const void* g, void* l) {
    __builtin_amdgcn_global_load_lds(
        (const __attribute__((address_space(1))) unsigned int*)g,
        (__attribute__((address_space(3))) unsigned int*)l,
        16, 0, 0);
}

// ---- kernel 1: fp32 -> fp8 e4m3 (scale 2^0) + fp32-exact row norms ----
__global__ __launch_bounds__(256) void prep_kernel(
        const float* __restrict__ inputs, const float* __restrict__ centers,
        unsigned char* __restrict__ Bq, unsigned char* __restrict__ Aq,
        float* __restrict__ x_sq, float* __restrict__ c_sq) {
    const int row  = blockIdx.x * 4 + (threadIdx.x >> 6);
    const int lane = threadIdx.x & 63;
    const bool is_x = row < N_ROWS;
    const float* src = is_x ? (inputs + (size_t)row * DIM)
                            : (centers + (size_t)(row - N_ROWS) * DIM);
    unsigned char* dst = is_x ? (Bq + (size_t)row * DIM)
                              : (Aq + (size_t)(row - N_ROWS) * DIM);
    const float4* s4 = (const float4*)src + lane * 4;
    float s = 0.0f;
    unsigned w[4];
    #pragma unroll
    for (int j = 0; j < 4; ++j) {
        float4 v = s4[j];
        int pk = __builtin_amdgcn_cvt_pk_fp8_f32(v.x, v.y, 0, false);
        pk     = __builtin_amdgcn_cvt_pk_fp8_f32(v.z, v.w, pk, true);
        w[j] = (unsigned)pk;
        s += v.x*v.x + v.y*v.y + v.z*v.z + v.w*v.w;
    }
    *(uint4*)(dst + lane * 16) = make_uint4(w[0], w[1], w[2], w[3]);
    #pragma unroll
    for (int off = 32; off > 0; off >>= 1) s += __shfl_down(s, off, 64);
    if (lane == 0) {
        if (is_x) x_sq[row] = s;
        else      c_sq[row - N_ROWS] = s;
    }
}

// ---- kernel 2: MX-fp8 GEMM (R7 shell) + phase-staggered K-loop ----
// out[m][n] = 2*sum_d A[m][d]*B[n][d] - c_sq[m] - x_sq[n]
// 128x128 tile, 4 waves, BK=128, A/B dbuf via global_load_lds (XOR swizzle).
// Block-parity phase stagger: odd (x^y) blocks start K at 512 and wrap, so
// co-resident blocks' barrier/memory bursts interleave instead of colliding.
// MFMA as D = B_op x A_op with scale 2^1 on the B side (folds the factor 2):
// C/D col(lane&15) = m, row(quad*4+reg) = n -> float4 stores along n.
#define BM 128
#define BN 128
#define BK 128
#define NITER (DIM / BK)

__device__ __forceinline__ i32x8 pack8(i32x4 lo, i32x4 hi) {
    i32x8 f;
    f[0]=lo[0]; f[1]=lo[1]; f[2]=lo[2]; f[3]=lo[3];
    f[4]=hi[0]; f[5]=hi[1]; f[6]=hi[2]; f[7]=hi[3];
    return f;
}

__global__ __launch_bounds__(256, 2) void gemm_kernel(
        const unsigned char* __restrict__ Aq,   // K_CENT x DIM fp8
        const unsigned char* __restrict__ Bq,   // N_ROWS x DIM fp8
        const float* __restrict__ x_sq, const float* __restrict__ c_sq,
        float* __restrict__ out) {              // K_CENT x N_ROWS
    __shared__ unsigned char sA[2][BM * BK];    // 2 x 16 KB
    __shared__ unsigned char sB[2][BN * BK];    // 2 x 16 KB

    const int t    = threadIdx.x;
    const int lane = t & 63;
    const int wave = t >> 6;
    const int wm   = (wave >> 1) * 64;
    const int wn   = (wave & 1) * 64;
    const int m0   = blockIdx.y * BM;
    const int n0   = blockIdx.x * BN;
    const int quad = lane >> 4;
    const int l16  = lane & 15;
    const int phase = ((blockIdx.x ^ blockIdx.y) & 1) * (NITER / 2);

    // staging: 1024 16-B units per matrix per iter; 4 per thread per matrix
    const unsigned char* gA[4];
    const unsigned char* gB[4];
    int ldsOff[4];
    #pragma unroll
    for (int i = 0; i < 4; ++i) {
        const int p = i * 256 + t;
        const int r = p >> 3;
        const int h = (p & 7) ^ (r & 7);
        gA[i] = Aq + (size_t)(m0 + r) * DIM + h * 16;
        gB[i] = Bq + (size_t)(n0 + r) * DIM + h * 16;
        ldsOff[i] = p * 16;
    }

    // fragment phys offsets: lane wants bytes [quad*32, quad*32+32) of its row
    const int off1 = (((quad << 1)    ) ^ (l16 & 7)) << 4;
    const int off2 = (((quad << 1) | 1) ^ (l16 & 7)) << 4;

    f32x4 acc[4][4] = {};                       // [mi][ni]

    // prologue: stage logical k-iter `phase` into buf 0
    {
        const int koff = phase * BK;
        #pragma unroll
        for (int i = 0; i < 4; ++i) {
            async_copy16(gA[i] + koff, &sA[0][ldsOff[i]]);
            async_copy16(gB[i] + koff, &sB[0][ldsOff[i]]);
        }
    }

    #pragma unroll
    for (int it = 0; it < NITER; ++it) {
        __syncthreads();                        // publishes buf it&1

        if (it + 1 < NITER) {
            const int nb = (it + 1) & 1;
            const int koff = (((it + 1 + phase) & (NITER - 1))) * BK;
            #pragma unroll
            for (int i = 0; i < 4; ++i) {
                async_copy16(gA[i] + koff, &sA[nb][ldsOff[i]]);
                async_copy16(gB[i] + koff, &sB[nb][ldsOff[i]]);
            }
        }

        const unsigned char* A = sA[it & 1];
        const unsigned char* B = sB[it & 1];
        i32x8 af[4], bf[4];
        #pragma unroll
        for (int mi = 0; mi < 4; ++mi) {
            const int rowByte = (wm + mi * 16 + l16) << 7;
            af[mi] = pack8(*(const i32x4*)(A + rowByte + off1),
                           *(const i32x4*)(A + rowByte + off2));
        }
        #pragma unroll
        for (int ni = 0; ni < 4; ++ni) {
            const int rowByte = (wn + ni * 16 + l16) << 7;
            bf[ni] = pack8(*(const i32x4*)(B + rowByte + off1),
                           *(const i32x4*)(B + rowByte + off2));
        }
        // D = B_op(A-arg) x A_op(B-arg); scale_a = 2^1 folds the "2*cross"
        #pragma unroll
        for (int mi = 0; mi < 4; ++mi)
            #pragma unroll
            for (int ni = 0; ni < 4; ++ni)
                acc[mi][ni] = __builtin_amdgcn_mfma_scale_f32_16x16x128_f8f6f4(
                    bf[ni], af[mi], acc[mi][ni],
                    0, 0,
                    0, 0x80808080,              // scale_a = 2^1
                    0, 0x7F7F7F7F);             // scale_b = 2^0
    }

    // epilogue: col(l16) = m, row(quad*4+reg) = n -> float4 store along n
    #pragma unroll
    for (int mi = 0; mi < 4; ++mi) {
        const int m = m0 + wm + mi * 16 + l16;
        const float cs = c_sq[m];
        float* orow = out + (size_t)m * N_ROWS;
        #pragma unroll
        for (int ni = 0; ni < 4; ++ni) {
            const int n = n0 + wn + ni * 16 + quad * 4;
            const float4 xs = *(const float4*)(x_sq + n);
            const f32x4 a = acc[mi][ni];        // a = 2*cross already
            float4 res;
            res.x = a[0] - cs - xs.x;
            res.y = a[1] - cs - xs.y;
            res.z = a[2] - cs - xs.z;
            res.w = a[3] - cs - xs.w;
            *(float4*)(orow + n) = res;
        }
    }
}

extern "C" void kernel_launch(void* const* d_in, const int* in_sizes, int n_in,
                              void* d_out, int out_size, void* d_ws, size_t ws_size,
                              hipStream_t stream) {
    const float* inputs  = (const float*)d_in[0];   // (8192, 1024) fp32
    const float* centers = (const float*)d_in[1];   // (1024, 1024) fp32
    float* out = (float*)d_out;                     // (1024, 8192) fp32

    unsigned char* Aq = (unsigned char*)d_ws;            // centers fp8: 1 MB
    unsigned char* Bq = Aq + (size_t)K_CENT * DIM;       // inputs fp8: 8 MB
    float* x_sq = (float*)(Bq + (size_t)N_ROWS * DIM);   // 8192
    float* c_sq = x_sq + N_ROWS;                         // 1024

    prep_kernel<<<(N_ROWS + K_CENT) / 4, 256, 0, stream>>>(
        inputs, centers, Bq, Aq, x_sq, c_sq);
    gemm_kernel<<<dim3(N_ROWS / BN, K_CENT / BM), 256, 0, stream>>>(
        Aq, Bq, x_sq, c_sq, out);
}